// Round 2
// baseline (139.938 us; speedup 1.0000x reference)
//
#include <hip/hip_runtime.h>
#include <cmath>
#include <cstdint>

constexpr float POS_THR = 0.5f;
constexpr float NEG_THR = 0.4f;
constexpr float F32_EPS = 1.1920928955078125e-07f;  // jnp.finfo(float32).eps

__device__ __forceinline__ float iou_one(const float4 a, const float area_a,
                                         const float4 g, const float area_g) {
    // EXACT op order of the reference (f32, no fma-contraction opportunities)
    float lx = fmaxf(a.x, g.x);
    float ly = fmaxf(a.y, g.y);
    float rx = fminf(a.z, g.z);
    float ry = fminf(a.w, g.w);
    float w  = fmaxf(rx - lx, 0.0f);
    float h  = fmaxf(ry - ly, 0.0f);
    float inter = w * h;
    return inter / (area_a + area_g - inter);
}

__device__ __forceinline__ float4 encode_box(const float4 a, const float4 g) {
    float ax = (a.x + a.z) * 0.5f;
    float ay = (a.y + a.w) * 0.5f;
    float aw = fmaxf(a.z - a.x, F32_EPS);
    float ah = fmaxf(a.w - a.y, F32_EPS);
    float gx = (g.x + g.z) * 0.5f;
    float gy = (g.y + g.w) * 0.5f;
    float gw = g.z - g.x;
    float gh = g.w - g.y;
    return make_float4((gx - ax) / aw, (gy - ay) / ah, logf(gw / aw), logf(gh / ah));
}

__global__ void init_ws(unsigned long long* __restrict__ ws, int m) {
    int j = blockIdx.x * blockDim.x + threadIdx.x;
    if (j < m) ws[j] = 0ull;
}

// One thread per anchor: row max/argmax -> cls, reg, pos (pre-forcing).
__global__ __launch_bounds__(256) void row_kernel(
    const float4* __restrict__ anchors, const float4* __restrict__ gts,
    const int* __restrict__ labels, int n, int m,
    float* __restrict__ out_cls, float4* __restrict__ out_reg,
    float* __restrict__ out_pos)
{
    __shared__ float4 sg[128];
    __shared__ float  sga[128];
    __shared__ float  slab[128];
    int t = threadIdx.x;
    if (t < m) {
        float4 g = gts[t];
        sg[t]  = g;
        sga[t] = (g.z - g.x) * (g.w - g.y);
        slab[t] = (float)labels[t];
    }
    __syncthreads();
    int i = blockIdx.x * blockDim.x + t;
    if (i >= n) return;
    float4 a = anchors[i];
    float area_a = (a.z - a.x) * (a.w - a.y);
    float best = -1.0f;
    int bestj = 0;
    #pragma unroll 4
    for (int j = 0; j < m; ++j) {
        float v = iou_one(a, area_a, sg[j], sga[j]);
        if (v > best) { best = v; bestj = j; }   // strict > : first-max tie-break
    }
    bool pos = best >= POS_THR;
    bool neg = (best < NEG_THR) && !pos;
    out_cls[i] = pos ? slab[bestj] : (neg ? 0.0f : -1.0f);
    out_pos[i] = pos ? 1.0f : 0.0f;
    float4 enc = make_float4(0.0f, 0.0f, 0.0f, 0.0f);
    if (pos) enc = encode_box(a, sg[bestj]);
    out_reg[i] = enc;
}

// gt-major column argmax. Packed key: (iou_bits << 32) | ~anchor_idx.
// iou >= 0 so float bits are order-preserving as u32; ~idx => min index wins ties.
__global__ __launch_bounds__(256) void col_kernel(
    const float4* __restrict__ anchors, const float4* __restrict__ gts,
    int n, int chunk, unsigned long long* __restrict__ ws)
{
    int j = blockIdx.y;
    float4 g = gts[j];
    float area_g = (g.z - g.x) * (g.w - g.y);
    int start = blockIdx.x * chunk + threadIdx.x;
    int end = min((int)((blockIdx.x + 1) * chunk), n);
    float best = -1.0f;
    int besti = -1;
    for (int i = start; i < end; i += blockDim.x) {
        float4 a = anchors[i];
        float area_a = (a.z - a.x) * (a.w - a.y);
        float v = iou_one(a, area_a, g, area_g);
        if (v > best) { best = v; besti = i; }   // ascending i => min idx within thread
    }
    unsigned long long key = 0ull;
    if (besti >= 0)
        key = ((unsigned long long)__float_as_uint(best) << 32) |
              (unsigned long long)(~(unsigned)besti);
    // wave-64 butterfly reduce on the packed key
    #pragma unroll
    for (int off = 32; off > 0; off >>= 1) {
        unsigned lo = (unsigned)key;
        unsigned hi = (unsigned)(key >> 32);
        lo = __shfl_xor(lo, off, 64);
        hi = __shfl_xor(hi, off, 64);
        unsigned long long o = ((unsigned long long)hi << 32) | lo;
        if (o > key) key = o;
    }
    if ((threadIdx.x & 63) == 0 && key != 0ull)
        atomicMax(ws + j, key);
}

// For each gt's winning anchor: force pos, recompute that anchor's row argmax
// (bit-identical expression) and rewrite cls/reg. Duplicate winners write
// identical values -> race-free in effect.
__global__ void fixup_kernel(
    const float4* __restrict__ anchors, const float4* __restrict__ gts,
    const int* __restrict__ labels, int n, int m,
    const unsigned long long* __restrict__ ws,
    float* __restrict__ out_cls, float4* __restrict__ out_reg,
    float* __restrict__ out_pos)
{
    int j = blockIdx.x * blockDim.x + threadIdx.x;
    if (j >= m) return;
    unsigned long long key = ws[j];
    int ai = (int)(~(unsigned)(key & 0xFFFFFFFFull));
    float4 a = anchors[ai];
    float area_a = (a.z - a.x) * (a.w - a.y);
    float best = -1.0f;
    int bestj = 0;
    for (int jj = 0; jj < m; ++jj) {
        float4 g = gts[jj];
        float area_g = (g.z - g.x) * (g.w - g.y);
        float v = iou_one(a, area_a, g, area_g);
        if (v > best) { best = v; bestj = jj; }
    }
    out_pos[ai] = 1.0f;
    out_cls[ai] = (float)labels[bestj];
    out_reg[ai] = encode_box(a, gts[bestj]);
}

extern "C" void kernel_launch(void* const* d_in, const int* in_sizes, int n_in,
                              void* d_out, int out_size, void* d_ws, size_t ws_size,
                              hipStream_t stream)
{
    const float4* anchors = (const float4*)d_in[0];
    const float4* gts     = (const float4*)d_in[1];
    const int*    labels  = (const int*)d_in[2];
    int n = in_sizes[0] / 4;   // 200000
    int m = in_sizes[1] / 4;   // 128

    float*  out     = (float*)d_out;
    float*  out_cls = out;                       // [n]
    float4* out_reg = (float4*)(out + n);        // [n][4] (byte offset n*4, 16B-aligned)
    float*  out_pos = out + 5 * (size_t)n;       // [n]
    unsigned long long* ws = (unsigned long long*)d_ws;   // [m] packed argmax keys

    init_ws<<<1, 256, 0, stream>>>(ws, m);
    row_kernel<<<(n + 255) / 256, 256, 0, stream>>>(anchors, gts, labels, n, m,
                                                    out_cls, out_reg, out_pos);
    const int CHUNKS = 16;
    int chunk = (n + CHUNKS - 1) / CHUNKS;       // 12500
    dim3 grid(CHUNKS, m);                        // 2048 blocks
    col_kernel<<<grid, 256, 0, stream>>>(anchors, gts, n, chunk, ws);
    fixup_kernel<<<1, 128, 0, stream>>>(anchors, gts, labels, n, m, ws,
                                        out_cls, out_reg, out_pos);
}

// Round 5
// 113.964 us; speedup vs baseline: 1.2279x; 1.2279x over previous
//
#include <hip/hip_runtime.h>
#include <cmath>
#include <cstdint>

typedef unsigned long long ull;

constexpr float POS_THR = 0.5f;
constexpr float NEG_THR = 0.4f;
constexpr float F32_EPS = 1.1920928955078125e-07f;  // jnp.finfo(float32).eps

__device__ __forceinline__ float iou_one(const float4 a, const float area_a,
                                         const float4 g, const float area_g) {
    // EXACT op order of the reference (f32; no fma-contraction opportunities)
    float lx = fmaxf(a.x, g.x);
    float ly = fmaxf(a.y, g.y);
    float rx = fminf(a.z, g.z);
    float ry = fminf(a.w, g.w);
    float w  = fmaxf(rx - lx, 0.0f);
    float h  = fmaxf(ry - ly, 0.0f);
    float inter = w * h;
    return inter / (area_a + area_g - inter);
}

__device__ __forceinline__ float4 encode_box(const float4 a, const float4 g) {
    float ax = (a.x + a.z) * 0.5f;
    float ay = (a.y + a.w) * 0.5f;
    float aw = fmaxf(a.z - a.x, F32_EPS);
    float ah = fmaxf(a.w - a.y, F32_EPS);
    float gx = (g.x + g.z) * 0.5f;
    float gy = (g.y + g.w) * 0.5f;
    float gw = g.z - g.x;
    float gh = g.w - g.y;
    return make_float4((gx - ax) / aw, (gy - ay) / ah, logf(gw / aw), logf(gh / ah));
}

__device__ __forceinline__ ull shfl_xor_u64(ull key, int off) {
    unsigned lo = (unsigned)key;
    unsigned hi = (unsigned)(key >> 32);
    lo = __shfl_xor(lo, off, 64);
    hi = __shfl_xor(hi, off, 64);
    return ((ull)hi << 32) | lo;
}

// One block = 256-anchor tile. Row outputs + per-block column-argmax keys.
// All tile data in LDS; loop reads are wave-broadcast (conflict-free).
__global__ __launch_bounds__(256) void fused_kernel(
    const float4* __restrict__ anchors, const float4* __restrict__ gts,
    const int* __restrict__ labels, int n, int m, int nblocks,
    float* __restrict__ out_cls, float4* __restrict__ out_reg,
    float* __restrict__ out_pos, ull* __restrict__ ws)
{
    __shared__ float4 sA[256];
    __shared__ float  sAa[256];
    __shared__ float4 sG[128];
    __shared__ float  sGa[128];
    __shared__ float  sLab[128];
    __shared__ ull    ck[256];

    const int t = threadIdx.x;
    const int base = blockIdx.x * 256;
    const int i = base + t;

    // Stage anchors (pad tail with zero-area boxes -> IoU exactly 0).
    float4 a = make_float4(0.0f, 0.0f, 0.0f, 0.0f);
    if (i < n) a = anchors[i];
    float area_a = (a.z - a.x) * (a.w - a.y);
    sA[t]  = a;
    sAa[t] = area_a;
    if (t < m) {
        float4 g = gts[t];
        sG[t]  = g;
        sGa[t] = (g.z - g.x) * (g.w - g.y);
        sLab[t] = (float)labels[t];
    }
    __syncthreads();

    // ---- Row pass: this thread's anchor vs all gts ----
    float best = -1.0f;
    int bestj = 0;
    #pragma unroll 8
    for (int j = 0; j < 128; ++j) {
        float v = iou_one(a, area_a, sG[j], sGa[j]);
        if (v > best) { best = v; bestj = j; }   // strict > : first-max tie-break
    }
    if (i < n) {
        bool pos = best >= POS_THR;
        bool neg = (best < NEG_THR) && !pos;
        out_cls[i] = pos ? sLab[bestj] : (neg ? 0.0f : -1.0f);
        out_pos[i] = pos ? 1.0f : 0.0f;
        float4 enc = make_float4(0.0f, 0.0f, 0.0f, 0.0f);
        if (pos) enc = encode_box(a, sG[bestj]);
        out_reg[i] = enc;
    }

    // ---- Column pass: 2 threads per gt, each scans half the anchor tile ----
    // key = (iou_bits << 32) | ~global_anchor_idx : max key => max iou, tie -> min idx
    const int j   = t & 127;
    const int off = (t >> 7) * 128;
    float4 g = sG[j];
    float area_g = sGa[j];
    float cbest = -1.0f;
    int   cbi   = 0;
    #pragma unroll 8
    for (int k = 0; k < 128; ++k) {
        int idx = off + k;
        float v = iou_one(sA[idx], sAa[idx], g, area_g);
        if (v > cbest) { cbest = v; cbi = idx; }  // ascending idx: min-idx tie-break
    }
    ck[t] = ((ull)__float_as_uint(cbest) << 32) | (ull)(~(unsigned)(base + cbi));
    __syncthreads();
    if (t < m) {
        ull k0 = ck[t], k1 = ck[t + 128];         // halves: idx(k0) < idx(k1)
        ull mk = k0 > k1 ? k0 : k1;
        ws[(size_t)t * nblocks + blockIdx.x] = mk;
    }
}

// One block per gt: reduce per-block keys -> winning anchor, then force-positive
// fixup (recompute that anchor's row argmax with the bit-identical expression).
// Duplicate winners across gts write identical values -> benign race.
__global__ __launch_bounds__(256) void reduce_fixup(
    const float4* __restrict__ anchors, const float4* __restrict__ gts,
    const int* __restrict__ labels, int n, int m, int nblocks,
    float* __restrict__ out_cls, float4* __restrict__ out_reg,
    float* __restrict__ out_pos, const ull* __restrict__ ws)
{
    __shared__ ull wk[4];
    __shared__ ull s_winner;
    const int j = blockIdx.x;
    const int t = threadIdx.x;
    const ull* wj = ws + (size_t)j * nblocks;

    ull key = 0ull;
    for (int b = t; b < nblocks; b += 256) {
        ull k = wj[b];
        if (k > key) key = k;
    }
    #pragma unroll
    for (int off = 32; off > 0; off >>= 1) {
        ull o = shfl_xor_u64(key, off);
        if (o > key) key = o;
    }
    if ((t & 63) == 0) wk[t >> 6] = key;
    __syncthreads();
    if (t == 0) {
        ull k = wk[0];
        #pragma unroll
        for (int w = 1; w < 4; ++w) if (wk[w] > k) k = wk[w];
        s_winner = k;
    }
    __syncthreads();
    const unsigned gi = ~(unsigned)(s_winner & 0xFFFFFFFFull);

    // Wave 0 recomputes row argmax for the winning anchor.
    if (t < 64) {
        float4 a = anchors[gi];
        float area_a = (a.z - a.x) * (a.w - a.y);
        ull k2 = 0ull;
        for (int jj = t; jj < m; jj += 64) {
            float4 g = gts[jj];
            float area_g = (g.z - g.x) * (g.w - g.y);
            float v = iou_one(a, area_a, g, area_g);
            ull kk = ((ull)__float_as_uint(v) << 32) | (ull)(~(unsigned)jj);
            if (kk > k2) k2 = kk;                 // tie -> smaller jj (larger ~jj)
        }
        #pragma unroll
        for (int off = 32; off > 0; off >>= 1) {
            ull o = shfl_xor_u64(k2, off);
            if (o > k2) k2 = o;
        }
        if (t == 0) {
            int bj = (int)(~(unsigned)(k2 & 0xFFFFFFFFull));
            out_pos[gi] = 1.0f;
            out_cls[gi] = (float)labels[bj];
            out_reg[gi] = encode_box(a, gts[bj]);
        }
    }
}

extern "C" void kernel_launch(void* const* d_in, const int* in_sizes, int n_in,
                              void* d_out, int out_size, void* d_ws, size_t ws_size,
                              hipStream_t stream)
{
    const float4* anchors = (const float4*)d_in[0];
    const float4* gts     = (const float4*)d_in[1];
    const int*    labels  = (const int*)d_in[2];
    int n = in_sizes[0] / 4;   // 200000
    int m = in_sizes[1] / 4;   // 128

    float*  out     = (float*)d_out;
    float*  out_cls = out;                       // [n]
    float4* out_reg = (float4*)(out + n);        // [n][4]
    float*  out_pos = out + 5 * (size_t)n;       // [n]
    ull*    ws      = (ull*)d_ws;                // [m][nblocks] packed keys

    int nblocks = (n + 255) / 256;               // 782
    fused_kernel<<<nblocks, 256, 0, stream>>>(anchors, gts, labels, n, m, nblocks,
                                              out_cls, out_reg, out_pos, ws);
    reduce_fixup<<<m, 256, 0, stream>>>(anchors, gts, labels, n, m, nblocks,
                                        out_cls, out_reg, out_pos, ws);
}

// Round 6
// 110.060 us; speedup vs baseline: 1.2715x; 1.0355x over previous
//
#include <hip/hip_runtime.h>
#include <cmath>
#include <cstdint>

typedef unsigned long long ull;

constexpr float POS_THR = 0.5f;
constexpr float NEG_THR = 0.4f;
constexpr float F32_EPS = 1.1920928955078125e-07f;  // jnp.finfo(float32).eps

__device__ __forceinline__ float iou_one(const float4 a, const float area_a,
                                         const float4 g, const float area_g) {
    // EXACT op order of the reference (f32; no fma-contraction opportunities)
    float lx = fmaxf(a.x, g.x);
    float ly = fmaxf(a.y, g.y);
    float rx = fminf(a.z, g.z);
    float ry = fminf(a.w, g.w);
    float w  = fmaxf(rx - lx, 0.0f);
    float h  = fmaxf(ry - ly, 0.0f);
    float inter = w * h;
    return inter / (area_a + area_g - inter);
}

__device__ __forceinline__ float4 encode_box(const float4 a, const float4 g) {
    float ax = (a.x + a.z) * 0.5f;
    float ay = (a.y + a.w) * 0.5f;
    float aw = fmaxf(a.z - a.x, F32_EPS);
    float ah = fmaxf(a.w - a.y, F32_EPS);
    float gx = (g.x + g.z) * 0.5f;
    float gy = (g.y + g.w) * 0.5f;
    float gw = g.z - g.x;
    float gh = g.w - g.y;
    return make_float4((gx - ax) / aw, (gy - ay) / ah, logf(gw / aw), logf(gh / ah));
}

__device__ __forceinline__ ull shfl_xor_u64(ull key, int off) {
    unsigned lo = (unsigned)key;
    unsigned hi = (unsigned)(key >> 32);
    lo = __shfl_xor(lo, off, 64);
    hi = __shfl_xor(hi, off, 64);
    return ((ull)hi << 32) | lo;
}

// One block = 128-anchor tile, 256 threads (2 threads per anchor / per gt).
// Row: thread (al, h) scans gts [h*64, h*64+64). Col: thread (j, h) scans
// local anchors [h*64, h*64+64). Packed keys (iou_bits<<32)|~idx make all
// merges order-insensitive with exact first-max (min-index) tie-breaking.
__global__ __launch_bounds__(256) void fused_kernel(
    const float4* __restrict__ anchors, const float4* __restrict__ gts,
    const int* __restrict__ labels, int n, int m, int nblocks,
    float* __restrict__ out_cls, float4* __restrict__ out_reg,
    float* __restrict__ out_pos, ull* __restrict__ ws)
{
    __shared__ float4 sA[128];
    __shared__ float  sAa[128];
    __shared__ float4 sG[128];
    __shared__ float  sGa[128];
    __shared__ float  sLab[128];
    __shared__ ull    ck[256];

    const int t = threadIdx.x;
    const int base = blockIdx.x * 128;

    // Stage: threads 0-127 load anchors (pad tail with zero-area -> IoU +0),
    // threads 128-255 load gts + areas + labels.
    if (t < 128) {
        int i = base + t;
        float4 a = make_float4(0.0f, 0.0f, 0.0f, 0.0f);
        if (i < n) a = anchors[i];
        sA[t]  = a;
        sAa[t] = (a.z - a.x) * (a.w - a.y);
    } else {
        int j = t - 128;
        float4 g = gts[j];
        sG[j]  = g;
        sGa[j] = (g.z - g.x) * (g.w - g.y);
        sLab[j] = (float)labels[j];
    }
    __syncthreads();

    const int al = t & 127;
    const int h  = t >> 7;

    // ---- Row pass: anchor al vs gts [h*64, h*64+64), two interleaved chains ----
    {
        float4 a = sA[al];
        float area_a = sAa[al];
        const int j0 = h * 64;
        ull kA = 0ull, kB = 0ull;
        #pragma unroll 4
        for (int k = 0; k < 32; ++k) {
            int jA = j0 + k;
            int jB = j0 + 32 + k;
            float vA = iou_one(a, area_a, sG[jA], sGa[jA]);
            float vB = iou_one(a, area_a, sG[jB], sGa[jB]);
            ull xA = ((ull)__float_as_uint(vA) << 32) | (ull)(~(unsigned)jA);
            ull xB = ((ull)__float_as_uint(vB) << 32) | (ull)(~(unsigned)jB);
            if (xA > kA) kA = xA;
            if (xB > kB) kB = xB;
        }
        ck[t] = kA > kB ? kA : kB;
    }
    __syncthreads();
    if (t < 128) {
        int i = base + t;
        ull k0 = ck[t], k1 = ck[t + 128];
        ull kk = k0 > k1 ? k0 : k1;
        if (i < n) {
            float best = __uint_as_float((unsigned)(kk >> 32));
            int bestj  = (int)(~(unsigned)(kk & 0xFFFFFFFFull));
            bool pos = best >= POS_THR;
            bool neg = (best < NEG_THR) && !pos;
            out_cls[i] = pos ? sLab[bestj] : (neg ? 0.0f : -1.0f);
            out_pos[i] = pos ? 1.0f : 0.0f;
            float4 enc = make_float4(0.0f, 0.0f, 0.0f, 0.0f);
            if (pos) enc = encode_box(sA[t], sG[bestj]);
            out_reg[i] = enc;
        }
    }
    __syncthreads();   // ck reused by col pass

    // ---- Col pass: gt al vs local anchors [h*64, h*64+64), two chains ----
    {
        float4 g = sG[al];
        float area_g = sGa[al];
        const int i0 = h * 64;
        ull kA = 0ull, kB = 0ull;
        #pragma unroll 4
        for (int k = 0; k < 32; ++k) {
            int iA = i0 + k;
            int iB = i0 + 32 + k;
            float vA = iou_one(sA[iA], sAa[iA], g, area_g);
            float vB = iou_one(sA[iB], sAa[iB], g, area_g);
            ull xA = ((ull)__float_as_uint(vA) << 32) | (ull)(~(unsigned)(base + iA));
            ull xB = ((ull)__float_as_uint(vB) << 32) | (ull)(~(unsigned)(base + iB));
            if (xA > kA) kA = xA;
            if (xB > kB) kB = xB;
        }
        ck[t] = kA > kB ? kA : kB;
    }
    __syncthreads();
    if (t < 128) {
        ull k0 = ck[t], k1 = ck[t + 128];
        ws[(size_t)t * nblocks + blockIdx.x] = k0 > k1 ? k0 : k1;
    }
}

// One block per gt: reduce per-block keys -> winning anchor, then force-positive
// fixup (recompute that anchor's row argmax with the bit-identical expression).
// Duplicate winners across gts write identical values -> benign race.
__global__ __launch_bounds__(256) void reduce_fixup(
    const float4* __restrict__ anchors, const float4* __restrict__ gts,
    const int* __restrict__ labels, int n, int m, int nblocks,
    float* __restrict__ out_cls, float4* __restrict__ out_reg,
    float* __restrict__ out_pos, const ull* __restrict__ ws)
{
    __shared__ ull wk[4];
    __shared__ ull s_winner;
    const int j = blockIdx.x;
    const int t = threadIdx.x;
    const ull* wj = ws + (size_t)j * nblocks;

    ull key = 0ull;
    for (int b = t; b < nblocks; b += 256) {
        ull k = wj[b];
        if (k > key) key = k;
    }
    #pragma unroll
    for (int off = 32; off > 0; off >>= 1) {
        ull o = shfl_xor_u64(key, off);
        if (o > key) key = o;
    }
    if ((t & 63) == 0) wk[t >> 6] = key;
    __syncthreads();
    if (t == 0) {
        ull k = wk[0];
        #pragma unroll
        for (int w = 1; w < 4; ++w) if (wk[w] > k) k = wk[w];
        s_winner = k;
    }
    __syncthreads();
    const unsigned gi = ~(unsigned)(s_winner & 0xFFFFFFFFull);

    // Wave 0 recomputes row argmax for the winning anchor.
    if (t < 64) {
        float4 a = anchors[gi];
        float area_a = (a.z - a.x) * (a.w - a.y);
        ull k2 = 0ull;
        for (int jj = t; jj < m; jj += 64) {
            float4 g = gts[jj];
            float area_g = (g.z - g.x) * (g.w - g.y);
            float v = iou_one(a, area_a, g, area_g);
            ull kk = ((ull)__float_as_uint(v) << 32) | (ull)(~(unsigned)jj);
            if (kk > k2) k2 = kk;                 // tie -> smaller jj (larger ~jj)
        }
        #pragma unroll
        for (int off = 32; off > 0; off >>= 1) {
            ull o = shfl_xor_u64(k2, off);
            if (o > k2) k2 = o;
        }
        if (t == 0) {
            int bj = (int)(~(unsigned)(k2 & 0xFFFFFFFFull));
            out_pos[gi] = 1.0f;
            out_cls[gi] = (float)labels[bj];
            out_reg[gi] = encode_box(a, gts[bj]);
        }
    }
}

extern "C" void kernel_launch(void* const* d_in, const int* in_sizes, int n_in,
                              void* d_out, int out_size, void* d_ws, size_t ws_size,
                              hipStream_t stream)
{
    const float4* anchors = (const float4*)d_in[0];
    const float4* gts     = (const float4*)d_in[1];
    const int*    labels  = (const int*)d_in[2];
    int n = in_sizes[0] / 4;   // 200000
    int m = in_sizes[1] / 4;   // 128

    float*  out     = (float*)d_out;
    float*  out_cls = out;                       // [n]
    float4* out_reg = (float4*)(out + n);        // [n][4]
    float*  out_pos = out + 5 * (size_t)n;       // [n]
    ull*    ws      = (ull*)d_ws;                // [m][nblocks] packed keys

    int nblocks = (n + 127) / 128;               // 1563
    fused_kernel<<<nblocks, 256, 0, stream>>>(anchors, gts, labels, n, m, nblocks,
                                              out_cls, out_reg, out_pos, ws);
    reduce_fixup<<<m, 256, 0, stream>>>(anchors, gts, labels, n, m, nblocks,
                                        out_cls, out_reg, out_pos, ws);
}

// Round 7
// 90.454 us; speedup vs baseline: 1.5471x; 1.2168x over previous
//
#include <hip/hip_runtime.h>
#include <cmath>
#include <cstdint>

typedef unsigned long long ull;

constexpr float POS_THR = 0.5f;
constexpr float NEG_THR = 0.4f;
constexpr float F32_EPS = 1.1920928955078125e-07f;  // jnp.finfo(float32).eps

__device__ __forceinline__ float iou_one(const float4 a, const float area_a,
                                         const float4 g, const float area_g) {
    // EXACT op order of the reference (f32; no fma-contraction opportunities)
    float lx = fmaxf(a.x, g.x);
    float ly = fmaxf(a.y, g.y);
    float rx = fminf(a.z, g.z);
    float ry = fminf(a.w, g.w);
    float w  = fmaxf(rx - lx, 0.0f);
    float h  = fmaxf(ry - ly, 0.0f);
    float inter = w * h;
    return inter / (area_a + area_g - inter);
}

__device__ __forceinline__ float4 encode_box(const float4 a, const float4 g) {
    float ax = (a.x + a.z) * 0.5f;
    float ay = (a.y + a.w) * 0.5f;
    float aw = fmaxf(a.z - a.x, F32_EPS);
    float ah = fmaxf(a.w - a.y, F32_EPS);
    float gx = (g.x + g.z) * 0.5f;
    float gy = (g.y + g.w) * 0.5f;
    float gw = g.z - g.x;
    float gh = g.w - g.y;
    return make_float4((gx - ax) / aw, (gy - ay) / ah, logf(gw / aw), logf(gh / ah));
}

__device__ __forceinline__ ull shfl_xor_u64(ull key, int off) {
    unsigned lo = (unsigned)key;
    unsigned hi = (unsigned)(key >> 32);
    lo = __shfl_xor(lo, off, 64);
    hi = __shfl_xor(hi, off, 64);
    return ((ull)hi << 32) | lo;
}

// One block = 128-anchor x 128-gt tile; 16x16 thread grid of 8x8 subtiles.
// EACH UNIQUE IoU IS COMPUTED EXACTLY ONCE, feeding both the row (per-anchor)
// and col (per-gt) running argmax. In-loop selects are float cmp + idx select;
// packed keys (iou_bits<<32)|~idx only at merge boundaries (order-insensitive,
// exact first-max / min-index tie-breaking).
__global__ __launch_bounds__(256) void fused_kernel(
    const float4* __restrict__ anchors, const float4* __restrict__ gts,
    const int* __restrict__ labels, int n, int m, int nblocks,
    float* __restrict__ out_cls, float4* __restrict__ out_reg,
    float* __restrict__ out_pos, ull* __restrict__ ws)
{
    __shared__ float4 sA[128];
    __shared__ float  sAa[128];
    __shared__ float4 sG[128];          // for encode_box in output phase
    __shared__ float  sLab[128];
    __shared__ ull    sK[128][17];      // padded merge buffer (row, then col)

    const int t = threadIdx.x;
    const int base = blockIdx.x * 128;

    // Stage: threads 0-127 anchors (tail padded zero-area -> IoU exactly +0),
    // threads 128-255 gts + labels (output-phase data only).
    if (t < 128) {
        int i = base + t;
        float4 a = make_float4(0.0f, 0.0f, 0.0f, 0.0f);
        if (i < n) a = anchors[i];
        sA[t]  = a;
        sAa[t] = (a.z - a.x) * (a.w - a.y);
    } else {
        int j = t - 128;
        sG[j] = gts[j];
        sLab[j] = (float)labels[j];
    }

    const int tx = t & 15;              // gt-strip index
    const int ty = t >> 4;              // anchor-strip index
    const int g0 = tx * 8;
    const int a0 = ty * 8;

    // gt strip to registers straight from global (2 KB hot, L1/L2-resident).
    float4 g[8];
    float  ga[8];
    #pragma unroll
    for (int j = 0; j < 8; ++j) {
        g[j]  = gts[g0 + j];
        ga[j] = (g[j].z - g[j].x) * (g[j].w - g[j].y);
    }

    float cbest[8];
    int   cbi[8];
    #pragma unroll
    for (int j = 0; j < 8; ++j) { cbest[j] = -1.0f; cbi[j] = 0; }

    __syncthreads();

    // ---- 8x8 subtile: one IoU per unique pair, dual row/col update ----
    for (int ai = 0; ai < 8; ++ai) {
        float4 a  = sA[a0 + ai];        // 4-way LDS broadcast (free)
        float  aa = sAa[a0 + ai];
        float rbest = -1.0f;
        int   rbj   = 0;
        #pragma unroll
        for (int j = 0; j < 8; ++j) {
            float v = iou_one(a, aa, g[j], ga[j]);
            if (v > rbest)    { rbest = v;    rbj = j;     }  // first-max in j
            if (v > cbest[j]) { cbest[j] = v; cbi[j] = ai; }  // first-max in ai
        }
        sK[a0 + ai][tx] = ((ull)__float_as_uint(rbest) << 32) |
                          (ull)(~(unsigned)(g0 + rbj));
    }
    __syncthreads();

    // ---- Row merge + outputs: thread t<128 owns anchor t ----
    if (t < 128) {
        ull k = sK[t][0];
        #pragma unroll
        for (int x = 1; x < 16; ++x) { ull o = sK[t][x]; if (o > k) k = o; }
        int i = base + t;
        if (i < n) {
            float best = __uint_as_float((unsigned)(k >> 32));
            int bestj  = (int)(~(unsigned)k);
            bool pos = best >= POS_THR;
            bool neg = (best < NEG_THR) && !pos;
            out_cls[i] = pos ? sLab[bestj] : (neg ? 0.0f : -1.0f);
            out_pos[i] = pos ? 1.0f : 0.0f;
            float4 enc = make_float4(0.0f, 0.0f, 0.0f, 0.0f);
            if (pos) enc = encode_box(sA[t], sG[bestj]);
            out_reg[i] = enc;
        }
    }
    __syncthreads();                    // sK reused for col merge

    // ---- Col partials: thread (ty,tx) -> columns [g0,g0+8) over anchors [a0,a0+8) ----
    #pragma unroll
    for (int j = 0; j < 8; ++j) {
        sK[g0 + j][ty] = ((ull)__float_as_uint(cbest[j]) << 32) |
                         (ull)(~(unsigned)(base + a0 + cbi[j]));
    }
    __syncthreads();

    // ---- Col merge: thread t<128 owns gt t ----
    if (t < 128) {
        ull k = sK[t][0];
        #pragma unroll
        for (int y = 1; y < 16; ++y) { ull o = sK[t][y]; if (o > k) k = o; }
        ws[(size_t)t * nblocks + blockIdx.x] = k;
    }
}

// One block per gt: reduce per-block keys -> winning anchor, then force-positive
// fixup (recompute that anchor's row argmax with the bit-identical expression).
// Duplicate winners across gts write identical values -> benign race.
__global__ __launch_bounds__(256) void reduce_fixup(
    const float4* __restrict__ anchors, const float4* __restrict__ gts,
    const int* __restrict__ labels, int n, int m, int nblocks,
    float* __restrict__ out_cls, float4* __restrict__ out_reg,
    float* __restrict__ out_pos, const ull* __restrict__ ws)
{
    __shared__ ull wk[4];
    __shared__ ull s_winner;
    const int j = blockIdx.x;
    const int t = threadIdx.x;
    const ull* wj = ws + (size_t)j * nblocks;

    ull key = 0ull;
    for (int b = t; b < nblocks; b += 256) {
        ull k = wj[b];
        if (k > key) key = k;
    }
    #pragma unroll
    for (int off = 32; off > 0; off >>= 1) {
        ull o = shfl_xor_u64(key, off);
        if (o > key) key = o;
    }
    if ((t & 63) == 0) wk[t >> 6] = key;
    __syncthreads();
    if (t == 0) {
        ull k = wk[0];
        #pragma unroll
        for (int w = 1; w < 4; ++w) if (wk[w] > k) k = wk[w];
        s_winner = k;
    }
    __syncthreads();
    const unsigned gi = ~(unsigned)(s_winner & 0xFFFFFFFFull);

    // Wave 0 recomputes row argmax for the winning anchor.
    if (t < 64) {
        float4 a = anchors[gi];
        float area_a = (a.z - a.x) * (a.w - a.y);
        ull k2 = 0ull;
        for (int jj = t; jj < m; jj += 64) {
            float4 g = gts[jj];
            float area_g = (g.z - g.x) * (g.w - g.y);
            float v = iou_one(a, area_a, g, area_g);
            ull kk = ((ull)__float_as_uint(v) << 32) | (ull)(~(unsigned)jj);
            if (kk > k2) k2 = kk;                 // tie -> smaller jj (larger ~jj)
        }
        #pragma unroll
        for (int off = 32; off > 0; off >>= 1) {
            ull o = shfl_xor_u64(k2, off);
            if (o > k2) k2 = o;
        }
        if (t == 0) {
            int bj = (int)(~(unsigned)(k2 & 0xFFFFFFFFull));
            out_pos[gi] = 1.0f;
            out_cls[gi] = (float)labels[bj];
            out_reg[gi] = encode_box(a, gts[bj]);
        }
    }
}

extern "C" void kernel_launch(void* const* d_in, const int* in_sizes, int n_in,
                              void* d_out, int out_size, void* d_ws, size_t ws_size,
                              hipStream_t stream)
{
    const float4* anchors = (const float4*)d_in[0];
    const float4* gts     = (const float4*)d_in[1];
    const int*    labels  = (const int*)d_in[2];
    int n = in_sizes[0] / 4;   // 200000
    int m = in_sizes[1] / 4;   // 128

    float*  out     = (float*)d_out;
    float*  out_cls = out;                       // [n]
    float4* out_reg = (float4*)(out + n);        // [n][4]
    float*  out_pos = out + 5 * (size_t)n;       // [n]
    ull*    ws      = (ull*)d_ws;                // [m][nblocks] packed keys

    int nblocks = (n + 127) / 128;               // 1563
    fused_kernel<<<nblocks, 256, 0, stream>>>(anchors, gts, labels, n, m, nblocks,
                                              out_cls, out_reg, out_pos, ws);
    reduce_fixup<<<m, 256, 0, stream>>>(anchors, gts, labels, n, m, nblocks,
                                        out_cls, out_reg, out_pos, ws);
}